// Round 1
// baseline (799.743 us; speedup 1.0000x reference)
//
#include <hip/hip_runtime.h>

// Per-edge Clebsch-Gordan tensor product:
//   out[i][p] = sum_{m,n} A[i][m] * B[i][n] * C[m][n][p]
// with m1 = m2 = mL = 5 (l = 2). Memory-bound streaming kernel.
//
// Layout trick: 4 edges per thread -> 20 floats per operand per thread
// = 5 aligned float4 loads/stores (byte offset tid*80 is 16-B aligned).
// C (125 floats) is read with wave-uniform indices -> scalar loads.

#define M1 5
#define M2 5
#define ML 5
#define EPT 4  // edges per thread

__global__ __launch_bounds__(256) void cg_combine_kernel(
    const float* __restrict__ A,
    const float* __restrict__ B,
    const float* __restrict__ C,
    float* __restrict__ out,
    int n_groups)  // = n_edges / EPT
{
    int t = blockIdx.x * blockDim.x + threadIdx.x;
    if (t >= n_groups) return;

    const float4* A4 = (const float4*)A + (size_t)t * 5;
    const float4* B4 = (const float4*)B + (size_t)t * 5;
    float4*       O4 = (float4*)out     + (size_t)t * 5;

    // Flat-layout registers: a[e*5+m] == A[(t*EPT+e)*5 + m]
    float a[EPT * M1];
    float b[EPT * M2];

#pragma unroll
    for (int k = 0; k < 5; ++k) {
        float4 va = A4[k];
        float4 vb = B4[k];
        a[4 * k + 0] = va.x; a[4 * k + 1] = va.y;
        a[4 * k + 2] = va.z; a[4 * k + 3] = va.w;
        b[4 * k + 0] = vb.x; b[4 * k + 1] = vb.y;
        b[4 * k + 2] = vb.z; b[4 * k + 3] = vb.w;
    }

    float acc[EPT * ML];
#pragma unroll
    for (int i = 0; i < EPT * ML; ++i) acc[i] = 0.0f;

#pragma unroll
    for (int m = 0; m < M1; ++m) {
#pragma unroll
        for (int n = 0; n < M2; ++n) {
            float ab0 = a[0 * M1 + m] * b[0 * M2 + n];
            float ab1 = a[1 * M1 + m] * b[1 * M2 + n];
            float ab2 = a[2 * M1 + m] * b[2 * M2 + n];
            float ab3 = a[3 * M1 + m] * b[3 * M2 + n];
#pragma unroll
            for (int p = 0; p < ML; ++p) {
                float c = C[(m * M2 + n) * ML + p];  // uniform -> s_load
                acc[0 * ML + p] = fmaf(ab0, c, acc[0 * ML + p]);
                acc[1 * ML + p] = fmaf(ab1, c, acc[1 * ML + p]);
                acc[2 * ML + p] = fmaf(ab2, c, acc[2 * ML + p]);
                acc[3 * ML + p] = fmaf(ab3, c, acc[3 * ML + p]);
            }
        }
    }

#pragma unroll
    for (int k = 0; k < 5; ++k) {
        float4 vo;
        vo.x = acc[4 * k + 0]; vo.y = acc[4 * k + 1];
        vo.z = acc[4 * k + 2]; vo.w = acc[4 * k + 3];
        O4[k] = vo;
    }
}

// Tail path (scalar, 1 edge per thread) in case n_edges % EPT != 0.
__global__ void cg_combine_tail_kernel(
    const float* __restrict__ A,
    const float* __restrict__ B,
    const float* __restrict__ C,
    float* __restrict__ out,
    int start_edge, int n_edges)
{
    int i = start_edge + blockIdx.x * blockDim.x + threadIdx.x;
    if (i >= n_edges) return;

    float a[M1], b[M2];
#pragma unroll
    for (int m = 0; m < M1; ++m) a[m] = A[(size_t)i * M1 + m];
#pragma unroll
    for (int n = 0; n < M2; ++n) b[n] = B[(size_t)i * M2 + n];

    float acc[ML];
#pragma unroll
    for (int p = 0; p < ML; ++p) acc[p] = 0.0f;

#pragma unroll
    for (int m = 0; m < M1; ++m) {
#pragma unroll
        for (int n = 0; n < M2; ++n) {
            float ab = a[m] * b[n];
#pragma unroll
            for (int p = 0; p < ML; ++p)
                acc[p] = fmaf(ab, C[(m * M2 + n) * ML + p], acc[p]);
        }
    }

#pragma unroll
    for (int p = 0; p < ML; ++p) out[(size_t)i * ML + p] = acc[p];
}

extern "C" void kernel_launch(void* const* d_in, const int* in_sizes, int n_in,
                              void* d_out, int out_size, void* d_ws, size_t ws_size,
                              hipStream_t stream) {
    const float* A = (const float*)d_in[0];
    const float* B = (const float*)d_in[1];
    const float* C = (const float*)d_in[2];
    float* out = (float*)d_out;

    const int n_edges  = in_sizes[0] / M1;   // 16,777,216
    const int n_groups = n_edges / EPT;      // 4,194,304
    const int tail     = n_edges % EPT;

    const int block = 256;
    const int grid  = (n_groups + block - 1) / block;
    cg_combine_kernel<<<grid, block, 0, stream>>>(A, B, C, out, n_groups);

    if (tail > 0) {
        const int start = n_groups * EPT;
        cg_combine_tail_kernel<<<1, 64, 0, stream>>>(A, B, C, out, start, n_edges);
    }
}